// Round 24
// baseline (124.170 us; speedup 1.0000x reference)
//
#include <hip/hip_runtime.h>
#include <hip/hip_bf16.h>

#define NPTS    10000
#define NRAYS   4096
#define PT32    320              // 32-point tiles -> 10240 padded
#define RT32    128              // 32-ray tiles
#define RGROUPS 32               // 4 ray-tiles (4 waves) per block
#define PCHUNKS 32               // point-tile chunks
#define TPC     (PT32 / PCHUNKS)     // 10 tiles per chunk
#define ABLK    32               // setup blocks, ray part (128 rt x 64 lanes)
#define BBLK    80               // setup blocks, point part (320 pt x 64 lanes)
#define LOG2E   1.44269504f

typedef float f16v __attribute__((ext_vector_type(16)));
typedef short s8v  __attribute__((ext_vector_type(8)));   // 8 bf16 = 4 VGPRs

// ---- static device scratch ----
// g_Br: per ray-tile, 3 B fragments {geo-d2, geo-pd, sh}  (rays = MFMA cols)
// g_Bp: per point-tile, 5 A fragments {d2+w1, pd+L0, c0, c1, c2} (points = rows)
//   A-frag k-slots (K=16): d2 uses k0..12, w1h/w1l at k13/k14;
//                          pd uses k0..10, L0h/L0l at k11/k12.
__device__ s8v   g_Br[RT32 * 3 * 64];
__device__ s8v   g_Bp[PT32 * 5 * 64];
__device__ float g_acc[NRAYS * 5];     // Sr,Sg,Sb,Sd,S
__device__ float g_oppart[BBLK];

__device__ __forceinline__ float fast_rcp(float x)  { return __builtin_amdgcn_rcpf(x); }
__device__ __forceinline__ float fast_exp2(float x) { return __builtin_amdgcn_exp2f(x); }
__device__ __forceinline__ float fast_sigmoid(float x) { return fast_rcp(1.0f + fast_exp2(-x * LOG2E)); }

__device__ __forceinline__ unsigned short bf16r(float x) {
    __hip_bfloat16 h = __float2bfloat16(x);
    return *reinterpret_cast<unsigned short*>(&h);
}
__device__ __forceinline__ float bf16f(unsigned short u) {
    return __uint_as_float((unsigned)u << 16);
}
__device__ __forceinline__ float bfhi(float x) { return bf16f(bf16r(x)); }

__device__ __forceinline__ s8v pk8(float a, float b, float c, float d,
                                   float e, float f, float g, float h) {
    s8v r;
    r[0] = (short)bf16r(a); r[1] = (short)bf16r(b);
    r[2] = (short)bf16r(c); r[3] = (short)bf16r(d);
    r[4] = (short)bf16r(e); r[5] = (short)bf16r(f);
    r[6] = (short)bf16r(g); r[7] = (short)bf16r(h);
    return r;
}

// ---------------- Kernel 1: setup (R21 — correctness-proven) -----------------
__global__ __launch_bounds__(256) void setup(const float* __restrict__ ro,
                                             const float* __restrict__ rd,
                                             const float* __restrict__ pos,
                                             const int*   __restrict__ sidx,
                                             const float* __restrict__ log_delta,
                                             const float* __restrict__ log_sigma,
                                             const float* __restrict__ raw_op,
                                             const float* __restrict__ shc) {
    if (blockIdx.x < ABLK) {
        int t = blockIdx.x * 256 + threadIdx.x;     // [0, 8192)
        int rt = t >> 6, lane = t & 63, half = lane >> 5;
        int r = rt * 32 + (lane & 31);
        if (half == 0) {                            // zero acc (each ray once)
            float* a = g_acc + (size_t)r * 5;
            a[0] = a[1] = a[2] = a[3] = a[4] = 0.0f;
        }
        float ox = ro[r * 3 + 0], oy = ro[r * 3 + 1], oz = ro[r * 3 + 2];
        float rdx = rd[r * 3 + 0], rdy = rd[r * 3 + 1], rdz = rd[r * 3 + 2];
        float inv = __builtin_amdgcn_rsqf(rdx * rdx + rdy * rdy + rdz * rdz);
        float x = rdx * inv, y = rdy * inv, z = rdz * inv;
        float oo = ox * ox + oy * oy + oz * oz;
        float od = ox * x + oy * y + oz * z;
        float ohx = bfhi(ox), olx = ox - ohx;
        float ohy = bfhi(oy), oly = oy - ohy;
        float ohz = bfhi(oz), olz = oz - ohz;
        float dhx = bfhi(x),  dlx = x - dhx;
        float dhy = bfhi(y),  dly = y - dhy;
        float dhz = bfhi(z),  dlz = z - dhz;
        float ooh = bfhi(oo), ool = oo - ooh;
        float odh = bfhi(od), odl = od - odh;
        float zz = z * z, xx = x * x, yy = y * y;
        float sh[16];
        sh[0]  = LOG2E * 0.282095f;
        sh[1]  = LOG2E * 0.488603f * y;
        sh[2]  = LOG2E * 0.488603f * z;
        sh[3]  = LOG2E * 0.488603f * x;
        sh[4]  = LOG2E * 1.092548f * x * y;
        sh[5]  = LOG2E * 1.092548f * y * z;
        sh[6]  = LOG2E * 0.315392f * (3.0f * zz - 1.0f);
        sh[7]  = LOG2E * 1.092548f * x * z;
        sh[8]  = LOG2E * 0.546274f * (xx - yy);
        sh[9]  = LOG2E * 0.590044f * y * (3.0f * xx - yy);
        sh[10] = LOG2E * 2.890611f * x * y * z;
        sh[11] = LOG2E * 0.457046f * y * (5.0f * zz - 1.0f);
        sh[12] = LOG2E * 0.373176f * z * (5.0f * zz - 3.0f);
        sh[13] = LOG2E * 0.457046f * x * (5.0f * zz - 1.0f);
        sh[14] = LOG2E * 1.445306f * z * (xx - yy);
        sh[15] = LOG2E * 0.590044f * x * (xx - 3.0f * yy);

        s8v B0 = half == 0 ? pk8(1, 1, ooh, ool, ohx, ohy, ohz, ohx)
                           : pk8(ohy, ohz, olx, oly, olz, 0, 0, 0);
        s8v B1 = half == 0 ? pk8(dhx, dhy, dhz, dhx, dhy, dhz, dlx, dly)
                           : pk8(dlz, odh, odl, 0, 0, 0, 0, 0);
        s8v B2 = half == 0 ? pk8(sh[0], sh[1], sh[2], sh[3], sh[4], sh[5], sh[6], sh[7])
                           : pk8(sh[8], sh[9], sh[10], sh[11], sh[12], sh[13], sh[14], sh[15]);
        s8v* pb = g_Br + (size_t)rt * 3 * 64 + lane;
        pb[0 * 64] = B0; pb[1 * 64] = B1; pb[2 * 64] = B2;
    } else {
        int bb = blockIdx.x - ABLK;
        int t  = bb * 256 + threadIdx.x;            // [0, 20480)
        int pt = t >> 6, lane = t & 63, half = lane >> 5;
        int n  = pt * 32 + (lane & 31);
        float px = 1e3f, py = 1e3f, pz = 1e3f, w1 = 0.0f, L0 = -100.0f, op = 0.0f;
        float C0[16], C1[16], C2[16];
#pragma unroll
        for (int k = 0; k < 16; ++k) { C0[k] = 0; C1[k] = 0; C2[k] = 0; }
        if (n < NPTS) {
            px = pos[n * 3 + 0]; py = pos[n * 3 + 1]; pz = pos[n * 3 + 2];
            int s = sidx[n];
            op = fast_sigmoid(raw_op[n]);
            w1 = -__expf(log_delta[s]) * LOG2E;
            float w0 = __expf(log_sigma[s]) * op;
            L0 = __log2f(w0);
            const float* c = shc + (size_t)n * 48;
#pragma unroll
            for (int k = 0; k < 16; ++k) {
                C0[k] = c[k * 3 + 0]; C1[k] = c[k * 3 + 1]; C2[k] = c[k * 3 + 2];
            }
        }
        float pp  = px * px + py * py + pz * pz;
        float phx = bfhi(px), plx = px - phx;
        float phy = bfhi(py), ply = py - phy;
        float phz = bfhi(pz), plz = pz - phz;
        float pph = bfhi(pp), ppl = pp - pph;
        float w1h = bfhi(w1), w1l = w1 - w1h;
        float L0h = bfhi(L0), L0l = L0 - L0h;

        s8v A0 = half == 0 ? pk8(pph, ppl, 1, 1, -2 * phx, -2 * phy, -2 * phz, -2 * plx)
                           : pk8(-2 * ply, -2 * plz, -2 * phx, -2 * phy, -2 * phz, w1h, w1l, 0);
        s8v A1 = half == 0 ? pk8(phx, phy, phz, plx, ply, plz, phx, phy)
                           : pk8(phz, -1, -1, L0h, L0l, 0, 0, 0);
        s8v A2 = half == 0 ? pk8(C0[0], C0[1], C0[2], C0[3], C0[4], C0[5], C0[6], C0[7])
                           : pk8(C0[8], C0[9], C0[10], C0[11], C0[12], C0[13], C0[14], C0[15]);
        s8v A3 = half == 0 ? pk8(C1[0], C1[1], C1[2], C1[3], C1[4], C1[5], C1[6], C1[7])
                           : pk8(C1[8], C1[9], C1[10], C1[11], C1[12], C1[13], C1[14], C1[15]);
        s8v A4 = half == 0 ? pk8(C2[0], C2[1], C2[2], C2[3], C2[4], C2[5], C2[6], C2[7])
                           : pk8(C2[8], C2[9], C2[10], C2[11], C2[12], C2[13], C2[14], C2[15]);
        s8v* pa = g_Bp + (size_t)pt * 5 * 64 + lane;
        pa[0 * 64] = A0; pa[1 * 64] = A1; pa[2 * 64] = A2; pa[3 * 64] = A3;
        pa[4 * 64] = A4;

        // opacity mean: count each point exactly once (half 0)
        __shared__ float blk;
        if (threadIdx.x == 0) blk = 0.0f;
        __syncthreads();
        float v = (half == 0) ? op : 0.0f;
#pragma unroll
        for (int off = 32; off > 0; off >>= 1) v += __shfl_down(v, off, 64);
        if ((threadIdx.x & 63) == 0) atomicAdd(&blk, v);
        __syncthreads();
        if (threadIdx.x == 0) g_oppart[bb] = blk;
    }
}

// ---------------- Kernel 2: main — 32x32x16 MFMA, A=points B=rays ------------
// R21 structure at 3 waves/EU: VGPR=96 fits the 170-reg cap comfortably (no
// allocator squeeze — the (256,4) cap of 128 triggered the R22 64-reg/scratch
// disaster), and a 3rd resident wave lets VALU-of-one overlap trans-of-another
// (per-tile budget: ~1088 cyc VALU + ~1536 cyc trans — trans is the heavy pipe).
__global__ __launch_bounds__(256, 3) void nerf_main() {
    int rg = blockIdx.x & (RGROUPS - 1);   // 32 consecutive blocks share a chunk
    int pc = blockIdx.x >> 5;
    int wv = threadIdx.x >> 6, lane = threadIdx.x & 63;
    int rt = rg * 4 + wv;

    const s8v* pr = g_Br + (size_t)rt * 3 * 64 + lane;
    s8v b0 = pr[0 * 64], b1 = pr[1 * 64], b2 = pr[2 * 64];
    // selector B-frags (in-register): ones at k13,k14 (w1) / k11,k12 (L0);
    // upper half lanes hold k8..15 as elements j=0..7.
    short one_bf = (short)0x3F80;
    s8v selw = {0, 0, 0, 0, 0, 0, 0, 0};
    s8v selL = {0, 0, 0, 0, 0, 0, 0, 0};
    if (lane >= 32) { selw[5] = one_bf; selw[6] = one_bf;
                      selL[3] = one_bf; selL[4] = one_bf; }
    f16v z = {0,0,0,0,0,0,0,0,0,0,0,0,0,0,0,0};

    float acc0 = 0.0f, acc1 = 0.0f, acc2 = 0.0f, acc3 = 0.0f, acc4 = 0.0f;

    const s8v* pa = g_Bp + (size_t)(pc * TPC) * 5 * 64 + lane;
#pragma unroll 1
    for (int ti = 0; ti < TPC; ++ti, pa += 5 * 64) {
        s8v a0 = pa[0 * 64], a1 = pa[1 * 64], a2 = pa[2 * 64], a3 = pa[3 * 64];
        s8v a4 = pa[4 * 64];
        // phase 1: geometry
        f16v c0 = __builtin_amdgcn_mfma_f32_32x32x16_bf16(a0, b0,   z, 0, 0, 0); // d2
        f16v c1 = __builtin_amdgcn_mfma_f32_32x32x16_bf16(a1, b1,   z, 0, 0, 0); // pd
        f16v c5 = __builtin_amdgcn_mfma_f32_32x32x16_bf16(a0, selw, z, 0, 0, 0); // w1
        f16v c6 = __builtin_amdgcn_mfma_f32_32x32x16_bf16(a1, selL, z, 0, 0, 0); // L0
        float cb[16];
#pragma unroll
        for (int i = 0; i < 16; ++i) {
            float d2  = c0[i], pd = c1[i];
            float inv = __builtin_amdgcn_rsqf(d2);
            float t   = 1.0f - pd * inv;
            float arg = fmaf(c5[i] * t, t, c6[i]);      // w1*t^2 + log2(w0)
            float contrib = fast_exp2(arg) * inv;
            cb[i] = contrib;
            acc4 += contrib;
            acc3  = fmaf(d2 * inv, contrib, acc3);
        }
        // phase 2: SH colors
        f16v c2 = __builtin_amdgcn_mfma_f32_32x32x16_bf16(a2, b2, z, 0, 0, 0);   // s0
        f16v c3 = __builtin_amdgcn_mfma_f32_32x32x16_bf16(a3, b2, z, 0, 0, 0);   // s1
        f16v c4 = __builtin_amdgcn_mfma_f32_32x32x16_bf16(a4, b2, z, 0, 0, 0);   // s2
#pragma unroll
        for (int i = 0; i < 16; ++i) {
            float e0 = 1.0f + fast_exp2(-c2[i]);
            float e1 = 1.0f + fast_exp2(-c3[i]);
            float e2 = 1.0f + fast_exp2(-c4[i]);
            float P  = e0 * e1, Pa = P * e2;
            float CI = cb[i] * fast_rcp(Pa);
            acc0 = fmaf(CI, e1 * e2, acc0);
            acc1 = fmaf(CI, e0 * e2, acc1);
            acc2 = fmaf(CI, P, acc2);
        }
    }

    // combine the two point-halves (lanes l and l+32 hold the same ray column)
    acc0 += __shfl_xor(acc0, 32, 64);
    acc1 += __shfl_xor(acc1, 32, 64);
    acc2 += __shfl_xor(acc2, 32, 64);
    acc3 += __shfl_xor(acc3, 32, 64);
    acc4 += __shfl_xor(acc4, 32, 64);
    if (lane < 32) {
        float* ac = g_acc + (size_t)(rt * 32 + lane) * 5;
        atomicAdd(ac + 0, acc0);
        atomicAdd(ac + 1, acc1);
        atomicAdd(ac + 2, acc2);
        atomicAdd(ac + 3, acc3);
        atomicAdd(ac + 4, acc4);
    }
}

// ---------------- Kernel 3: finalize (f32 output) ----------------------------
__global__ void finalize(float* __restrict__ out) {
    int r = blockIdx.x * blockDim.x + threadIdx.x;
    if (r >= NRAYS) return;
    float opv = 0.0f;
    for (int i = 0; i < BBLK; ++i) opv += g_oppart[i];
    const float* a = g_acc + (size_t)r * 5;
    float inv = fast_rcp(a[4] + 1e-8f);
    out[r * 3 + 0]     = a[0] * inv;
    out[r * 3 + 1]     = a[1] * inv;
    out[r * 3 + 2]     = a[2] * inv;
    out[NRAYS * 3 + r] = a[3] * inv;
    out[NRAYS * 4 + r] = opv * (1.0f / NPTS);
}

extern "C" void kernel_launch(void* const* d_in, const int* in_sizes, int n_in,
                              void* d_out, int out_size, void* d_ws, size_t ws_size,
                              hipStream_t stream) {
    const float* rays_o    = (const float*)d_in[0];
    const float* rays_d    = (const float*)d_in[1];
    const float* positions = (const float*)d_in[2];
    const int*   sidx      = (const int*)d_in[3];
    const float* log_delta = (const float*)d_in[4];
    const float* log_sigma = (const float*)d_in[5];
    const float* raw_op    = (const float*)d_in[6];
    const float* shc       = (const float*)d_in[7];

    setup<<<ABLK + BBLK, 256, 0, stream>>>(
        rays_o, rays_d, positions, sidx, log_delta, log_sigma, raw_op, shc);
    nerf_main<<<RGROUPS * PCHUNKS, 256, 0, stream>>>();
    finalize<<<NRAYS / 256, 256, 0, stream>>>((float*)d_out);
}

// Round 25
// 113.623 us; speedup vs baseline: 1.0928x; 1.0928x over previous
//
#include <hip/hip_runtime.h>
#include <hip/hip_bf16.h>

#define NPTS    10000
#define NRAYS   4096
#define PT32    320              // 32-point tiles -> 10240 padded
#define RT32    128              // 32-ray tiles
#define RGROUPS 32               // 4 ray-tiles (4 waves) per block
#define PCHUNKS 32               // point-tile chunks
#define TPC     (PT32 / PCHUNKS)     // 10 tiles per chunk
#define ABLK    32               // setup blocks, ray part (128 rt x 64 lanes)
#define BBLK    80               // setup blocks, point part (320 pt x 64 lanes)
#define LOG2E   1.44269504f

typedef float f16v __attribute__((ext_vector_type(16)));
typedef float v2   __attribute__((ext_vector_type(2)));
typedef short s8v  __attribute__((ext_vector_type(8)));   // 8 bf16 = 4 VGPRs

// ---- static device scratch ----
// g_Br: per ray-tile, 3 B fragments {geo-d2, geo-pd, sh}  (rays = MFMA cols)
// g_Bp: per point-tile, 5 A fragments {d2+w1, pd+L0, c0, c1, c2} (points = rows)
__device__ s8v   g_Br[RT32 * 3 * 64];
__device__ s8v   g_Bp[PT32 * 5 * 64];
__device__ float g_acc[NRAYS * 5];     // Sr,Sg,Sb,Sd,S
__device__ float g_oppart[BBLK];

__device__ __forceinline__ float fast_rcp(float x)  { return __builtin_amdgcn_rcpf(x); }
__device__ __forceinline__ float fast_exp2(float x) { return __builtin_amdgcn_exp2f(x); }
__device__ __forceinline__ float fast_sigmoid(float x) { return fast_rcp(1.0f + fast_exp2(-x * LOG2E)); }

__device__ __forceinline__ unsigned short bf16r(float x) {
    __hip_bfloat16 h = __float2bfloat16(x);
    return *reinterpret_cast<unsigned short*>(&h);
}
__device__ __forceinline__ float bf16f(unsigned short u) {
    return __uint_as_float((unsigned)u << 16);
}
__device__ __forceinline__ float bfhi(float x) { return bf16f(bf16r(x)); }

__device__ __forceinline__ s8v pk8(float a, float b, float c, float d,
                                   float e, float f, float g, float h) {
    s8v r;
    r[0] = (short)bf16r(a); r[1] = (short)bf16r(b);
    r[2] = (short)bf16r(c); r[3] = (short)bf16r(d);
    r[4] = (short)bf16r(e); r[5] = (short)bf16r(f);
    r[6] = (short)bf16r(g); r[7] = (short)bf16r(h);
    return r;
}

__device__ __forceinline__ v2 fmav(v2 a, v2 b, v2 c) { return __builtin_elementwise_fma(a, b, c); }

// ---------------- Kernel 1: setup (R21 — correctness-proven) -----------------
__global__ __launch_bounds__(256) void setup(const float* __restrict__ ro,
                                             const float* __restrict__ rd,
                                             const float* __restrict__ pos,
                                             const int*   __restrict__ sidx,
                                             const float* __restrict__ log_delta,
                                             const float* __restrict__ log_sigma,
                                             const float* __restrict__ raw_op,
                                             const float* __restrict__ shc) {
    if (blockIdx.x < ABLK) {
        int t = blockIdx.x * 256 + threadIdx.x;     // [0, 8192)
        int rt = t >> 6, lane = t & 63, half = lane >> 5;
        int r = rt * 32 + (lane & 31);
        if (half == 0) {                            // zero acc (each ray once)
            float* a = g_acc + (size_t)r * 5;
            a[0] = a[1] = a[2] = a[3] = a[4] = 0.0f;
        }
        float ox = ro[r * 3 + 0], oy = ro[r * 3 + 1], oz = ro[r * 3 + 2];
        float rdx = rd[r * 3 + 0], rdy = rd[r * 3 + 1], rdz = rd[r * 3 + 2];
        float inv = __builtin_amdgcn_rsqf(rdx * rdx + rdy * rdy + rdz * rdz);
        float x = rdx * inv, y = rdy * inv, z = rdz * inv;
        float oo = ox * ox + oy * oy + oz * oz;
        float od = ox * x + oy * y + oz * z;
        float ohx = bfhi(ox), olx = ox - ohx;
        float ohy = bfhi(oy), oly = oy - ohy;
        float ohz = bfhi(oz), olz = oz - ohz;
        float dhx = bfhi(x),  dlx = x - dhx;
        float dhy = bfhi(y),  dly = y - dhy;
        float dhz = bfhi(z),  dlz = z - dhz;
        float ooh = bfhi(oo), ool = oo - ooh;
        float odh = bfhi(od), odl = od - odh;
        float zz = z * z, xx = x * x, yy = y * y;
        float sh[16];
        sh[0]  = LOG2E * 0.282095f;
        sh[1]  = LOG2E * 0.488603f * y;
        sh[2]  = LOG2E * 0.488603f * z;
        sh[3]  = LOG2E * 0.488603f * x;
        sh[4]  = LOG2E * 1.092548f * x * y;
        sh[5]  = LOG2E * 1.092548f * y * z;
        sh[6]  = LOG2E * 0.315392f * (3.0f * zz - 1.0f);
        sh[7]  = LOG2E * 1.092548f * x * z;
        sh[8]  = LOG2E * 0.546274f * (xx - yy);
        sh[9]  = LOG2E * 0.590044f * y * (3.0f * xx - yy);
        sh[10] = LOG2E * 2.890611f * x * y * z;
        sh[11] = LOG2E * 0.457046f * y * (5.0f * zz - 1.0f);
        sh[12] = LOG2E * 0.373176f * z * (5.0f * zz - 3.0f);
        sh[13] = LOG2E * 0.457046f * x * (5.0f * zz - 1.0f);
        sh[14] = LOG2E * 1.445306f * z * (xx - yy);
        sh[15] = LOG2E * 0.590044f * x * (xx - 3.0f * yy);

        s8v B0 = half == 0 ? pk8(1, 1, ooh, ool, ohx, ohy, ohz, ohx)
                           : pk8(ohy, ohz, olx, oly, olz, 0, 0, 0);
        s8v B1 = half == 0 ? pk8(dhx, dhy, dhz, dhx, dhy, dhz, dlx, dly)
                           : pk8(dlz, odh, odl, 0, 0, 0, 0, 0);
        s8v B2 = half == 0 ? pk8(sh[0], sh[1], sh[2], sh[3], sh[4], sh[5], sh[6], sh[7])
                           : pk8(sh[8], sh[9], sh[10], sh[11], sh[12], sh[13], sh[14], sh[15]);
        s8v* pb = g_Br + (size_t)rt * 3 * 64 + lane;
        pb[0 * 64] = B0; pb[1 * 64] = B1; pb[2 * 64] = B2;
    } else {
        int bb = blockIdx.x - ABLK;
        int t  = bb * 256 + threadIdx.x;            // [0, 20480)
        int pt = t >> 6, lane = t & 63, half = lane >> 5;
        int n  = pt * 32 + (lane & 31);
        float px = 1e3f, py = 1e3f, pz = 1e3f, w1 = 0.0f, L0 = -100.0f, op = 0.0f;
        float C0[16], C1[16], C2[16];
#pragma unroll
        for (int k = 0; k < 16; ++k) { C0[k] = 0; C1[k] = 0; C2[k] = 0; }
        if (n < NPTS) {
            px = pos[n * 3 + 0]; py = pos[n * 3 + 1]; pz = pos[n * 3 + 2];
            int s = sidx[n];
            op = fast_sigmoid(raw_op[n]);
            w1 = -__expf(log_delta[s]) * LOG2E;
            float w0 = __expf(log_sigma[s]) * op;
            L0 = __log2f(w0);
            const float* c = shc + (size_t)n * 48;
#pragma unroll
            for (int k = 0; k < 16; ++k) {
                C0[k] = c[k * 3 + 0]; C1[k] = c[k * 3 + 1]; C2[k] = c[k * 3 + 2];
            }
        }
        float pp  = px * px + py * py + pz * pz;
        float phx = bfhi(px), plx = px - phx;
        float phy = bfhi(py), ply = py - phy;
        float phz = bfhi(pz), plz = pz - phz;
        float pph = bfhi(pp), ppl = pp - pph;
        float w1h = bfhi(w1), w1l = w1 - w1h;
        float L0h = bfhi(L0), L0l = L0 - L0h;

        s8v A0 = half == 0 ? pk8(pph, ppl, 1, 1, -2 * phx, -2 * phy, -2 * phz, -2 * plx)
                           : pk8(-2 * ply, -2 * plz, -2 * phx, -2 * phy, -2 * phz, w1h, w1l, 0);
        s8v A1 = half == 0 ? pk8(phx, phy, phz, plx, ply, plz, phx, phy)
                           : pk8(phz, -1, -1, L0h, L0l, 0, 0, 0);
        s8v A2 = half == 0 ? pk8(C0[0], C0[1], C0[2], C0[3], C0[4], C0[5], C0[6], C0[7])
                           : pk8(C0[8], C0[9], C0[10], C0[11], C0[12], C0[13], C0[14], C0[15]);
        s8v A3 = half == 0 ? pk8(C1[0], C1[1], C1[2], C1[3], C1[4], C1[5], C1[6], C1[7])
                           : pk8(C1[8], C1[9], C1[10], C1[11], C1[12], C1[13], C1[14], C1[15]);
        s8v A4 = half == 0 ? pk8(C2[0], C2[1], C2[2], C2[3], C2[4], C2[5], C2[6], C2[7])
                           : pk8(C2[8], C2[9], C2[10], C2[11], C2[12], C2[13], C2[14], C2[15]);
        s8v* pa = g_Bp + (size_t)pt * 5 * 64 + lane;
        pa[0 * 64] = A0; pa[1 * 64] = A1; pa[2 * 64] = A2; pa[3 * 64] = A3;
        pa[4 * 64] = A4;

        // opacity mean: count each point exactly once (half 0)
        __shared__ float blk;
        if (threadIdx.x == 0) blk = 0.0f;
        __syncthreads();
        float v = (half == 0) ? op : 0.0f;
#pragma unroll
        for (int off = 32; off > 0; off >>= 1) v += __shfl_down(v, off, 64);
        if ((threadIdx.x & 63) == 0) atomicAdd(&blk, v);
        __syncthreads();
        if (threadIdx.x == 0) g_oppart[bb] = blk;
    }
}

// ---------------- Kernel 2: main — R21 + packed-f32 epilogue -----------------
// Element pairs processed as v2 (v_pk_fma_f32 etc., full-rate, R6-proven);
// trans ops stay scalar. VALU issue per tile ~halves; launch bounds stay
// (256,2) — every other occupancy setting triggers allocator spills (R22/R24).
__global__ __launch_bounds__(256, 2) void nerf_main() {
    int rg = blockIdx.x & (RGROUPS - 1);   // 32 consecutive blocks share a chunk
    int pc = blockIdx.x >> 5;
    int wv = threadIdx.x >> 6, lane = threadIdx.x & 63;
    int rt = rg * 4 + wv;

    const s8v* pr = g_Br + (size_t)rt * 3 * 64 + lane;
    s8v b0 = pr[0 * 64], b1 = pr[1 * 64], b2 = pr[2 * 64];
    short one_bf = (short)0x3F80;
    s8v selw = {0, 0, 0, 0, 0, 0, 0, 0};
    s8v selL = {0, 0, 0, 0, 0, 0, 0, 0};
    if (lane >= 32) { selw[5] = one_bf; selw[6] = one_bf;
                      selL[3] = one_bf; selL[4] = one_bf; }
    f16v z = {0,0,0,0,0,0,0,0,0,0,0,0,0,0,0,0};
    const v2 one2 = {1.0f, 1.0f};

    v2 acc0 = {0, 0}, acc1 = acc0, acc2 = acc0, acc3 = acc0, acc4 = acc0;

    const s8v* pa = g_Bp + (size_t)(pc * TPC) * 5 * 64 + lane;
#pragma unroll 1
    for (int ti = 0; ti < TPC; ++ti, pa += 5 * 64) {
        s8v a0 = pa[0 * 64], a1 = pa[1 * 64], a2 = pa[2 * 64], a3 = pa[3 * 64];
        s8v a4 = pa[4 * 64];
        // phase 1: geometry
        f16v c0 = __builtin_amdgcn_mfma_f32_32x32x16_bf16(a0, b0,   z, 0, 0, 0); // d2
        f16v c1 = __builtin_amdgcn_mfma_f32_32x32x16_bf16(a1, b1,   z, 0, 0, 0); // pd
        f16v c5 = __builtin_amdgcn_mfma_f32_32x32x16_bf16(a0, selw, z, 0, 0, 0); // w1
        f16v c6 = __builtin_amdgcn_mfma_f32_32x32x16_bf16(a1, selL, z, 0, 0, 0); // L0
        v2 cb[8];
#pragma unroll
        for (int j = 0; j < 8; ++j) {
            v2 d2  = {c0[2 * j], c0[2 * j + 1]};
            v2 pd  = {c1[2 * j], c1[2 * j + 1]};
            v2 w1v = {c5[2 * j], c5[2 * j + 1]};
            v2 L0v = {c6[2 * j], c6[2 * j + 1]};
            v2 inv;
            inv.x = __builtin_amdgcn_rsqf(d2.x);
            inv.y = __builtin_amdgcn_rsqf(d2.y);
            v2 t   = fmav(-pd, inv, one2);
            v2 arg = fmav(w1v * t, t, L0v);
            v2 e;
            e.x = fast_exp2(arg.x);
            e.y = fast_exp2(arg.y);
            v2 contrib = e * inv;
            cb[j] = contrib;
            acc4 = acc4 + contrib;
            acc3 = fmav(d2 * inv, contrib, acc3);
        }
        // phase 2: SH colors
        f16v c2 = __builtin_amdgcn_mfma_f32_32x32x16_bf16(a2, b2, z, 0, 0, 0);   // s0
        f16v c3 = __builtin_amdgcn_mfma_f32_32x32x16_bf16(a3, b2, z, 0, 0, 0);   // s1
        f16v c4 = __builtin_amdgcn_mfma_f32_32x32x16_bf16(a4, b2, z, 0, 0, 0);   // s2
#pragma unroll
        for (int j = 0; j < 8; ++j) {
            v2 e0, e1, e2;
            e0.x = fast_exp2(-c2[2 * j]); e0.y = fast_exp2(-c2[2 * j + 1]);
            e1.x = fast_exp2(-c3[2 * j]); e1.y = fast_exp2(-c3[2 * j + 1]);
            e2.x = fast_exp2(-c4[2 * j]); e2.y = fast_exp2(-c4[2 * j + 1]);
            e0 = e0 + one2; e1 = e1 + one2; e2 = e2 + one2;
            v2 P  = e0 * e1, Pa = P * e2;
            v2 rp;
            rp.x = fast_rcp(Pa.x);
            rp.y = fast_rcp(Pa.y);
            v2 CI = cb[j] * rp;
            acc0 = fmav(CI, e1 * e2, acc0);
            acc1 = fmav(CI, e0 * e2, acc1);
            acc2 = fmav(CI, P, acc2);
        }
    }

    // v2 -> scalar, then combine the two point-halves
    float s0 = acc0.x + acc0.y, s1 = acc1.x + acc1.y, s2 = acc2.x + acc2.y;
    float s3 = acc3.x + acc3.y, s4 = acc4.x + acc4.y;
    s0 += __shfl_xor(s0, 32, 64);
    s1 += __shfl_xor(s1, 32, 64);
    s2 += __shfl_xor(s2, 32, 64);
    s3 += __shfl_xor(s3, 32, 64);
    s4 += __shfl_xor(s4, 32, 64);
    if (lane < 32) {
        float* ac = g_acc + (size_t)(rt * 32 + lane) * 5;
        atomicAdd(ac + 0, s0);
        atomicAdd(ac + 1, s1);
        atomicAdd(ac + 2, s2);
        atomicAdd(ac + 3, s3);
        atomicAdd(ac + 4, s4);
    }
}

// ---------------- Kernel 3: finalize (f32 output) ----------------------------
__global__ void finalize(float* __restrict__ out) {
    int r = blockIdx.x * blockDim.x + threadIdx.x;
    if (r >= NRAYS) return;
    float opv = 0.0f;
    for (int i = 0; i < BBLK; ++i) opv += g_oppart[i];
    const float* a = g_acc + (size_t)r * 5;
    float inv = fast_rcp(a[4] + 1e-8f);
    out[r * 3 + 0]     = a[0] * inv;
    out[r * 3 + 1]     = a[1] * inv;
    out[r * 3 + 2]     = a[2] * inv;
    out[NRAYS * 3 + r] = a[3] * inv;
    out[NRAYS * 4 + r] = opv * (1.0f / NPTS);
}

extern "C" void kernel_launch(void* const* d_in, const int* in_sizes, int n_in,
                              void* d_out, int out_size, void* d_ws, size_t ws_size,
                              hipStream_t stream) {
    const float* rays_o    = (const float*)d_in[0];
    const float* rays_d    = (const float*)d_in[1];
    const float* positions = (const float*)d_in[2];
    const int*   sidx      = (const int*)d_in[3];
    const float* log_delta = (const float*)d_in[4];
    const float* log_sigma = (const float*)d_in[5];
    const float* raw_op    = (const float*)d_in[6];
    const float* shc       = (const float*)d_in[7];

    setup<<<ABLK + BBLK, 256, 0, stream>>>(
        rays_o, rays_d, positions, sidx, log_delta, log_sigma, raw_op, shc);
    nerf_main<<<RGROUPS * PCHUNKS, 256, 0, stream>>>();
    finalize<<<NRAYS / 256, 256, 0, stream>>>((float*)d_out);
}